// Round 4
// baseline (127.844 us; speedup 1.0000x reference)
//
#include <hip/hip_runtime.h>
#include <hip/hip_bf16.h>
#include <math.h>

#define B_  2
#define S_  2048
#define H_  16
#define D_  64
#define SST 40   // score-strip stride (shorts): 80 B rows, 16B-aligned

typedef __attribute__((ext_vector_type(8))) short bf16x8_t;
typedef __attribute__((ext_vector_type(4))) float f32x4_t;

__device__ __forceinline__ unsigned short f2bf(float f) {
    __hip_bfloat16 h = __float2bfloat16(f);
    return __builtin_bit_cast(unsigned short, h);
}

// async global->LDS, 16B per lane; LDS dest = wave-uniform base + lane*16
__device__ __forceinline__ void async16(const unsigned short* g, unsigned short* l) {
    __builtin_amdgcn_global_load_lds(
        (const __attribute__((address_space(1))) unsigned int*)g,
        (__attribute__((address_space(3))) unsigned int*)l, 16, 0, 0);
}

#define WAITV2 asm volatile("s_waitcnt vmcnt(2)" ::: "memory")
#define WAITV0 asm volatile("s_waitcnt vmcnt(0)" ::: "memory")
#define BAR    asm volatile("s_barrier" ::: "memory")

// ---------------- kernel 0: trig/decay tables ----------------
// rot4[s*32+i] = (cos*xsc, sin*xsc, cos/xsc, sin/xsc)   [1 MB]
// g2[h*2048+s] = (gamma^s, gamma^-s)                    [256 KB]
__global__ __launch_bounds__(256) void table_kernel(float4* __restrict__ rot4,
                                                    float2* __restrict__ g2) {
    int tid = blockIdx.x * 256 + threadIdx.x;   // 0..65535
    int i   = tid & 31;                         // rotation pair index
    int s   = tid >> 5;                         // 0..2047
    float pos = (float)s;

    float bsc  = (2.0f * (float)i + 25.6f) / 89.6f;
    float xsc  = exp2f(log2f(bsc) * pos * (1.0f / 512.0f));
    float invf = exp2f(-(float)i * (13.287712379549449f / 32.0f));
    float ang  = pos * invf;
    float kq = rintf(ang * 0.15915494309189535f);
    float r  = fmaf(kq, -6.2831853071795865f, ang);
    float sn = sinf(r), cs = cosf(r);
    float rxs = 1.0f / xsc;
    rot4[tid] = make_float4(cs * xsc, sn * xsc, cs * rxs, sn * rxs);

    if (tid < H_ * S_) {
        int hh = tid >> 11, ss = tid & 2047;
        float lnv   = -3.4657359027997265f + (float)hh * (-0.18483924814931874f);
        float l2g   = log2f(1.0f - expf(lnv));
        g2[tid] = make_float2(exp2f((float)ss * l2g), exp2f(-(float)ss * l2g));
    }
}

// ---------------- kernel 1: streaming prep ----------
// qb/kb keep the INPUT layout [b][s][1024] (bf16): QK path is a pure
// contiguous streamer (one full row per block).
// blocks [0,4096):     QK — one row of Q and K per block.
// blocks [4096,5120):  V  — transpose path, unchanged (proven).
__global__ __launch_bounds__(256) void prep_kernel(const float* __restrict__ Q,
                                                   const float* __restrict__ K,
                                                   const float* __restrict__ V,
                                                   const float4* __restrict__ rot4,
                                                   const float2* __restrict__ g2,
                                                   unsigned short* __restrict__ qb,
                                                   unsigned short* __restrict__ kb,
                                                   unsigned short* __restrict__ vt) {
    __shared__ float tile[64 * 65];
    int t   = threadIdx.x;
    int bid = blockIdx.x;

    if (bid < 4096) {
        int r   = bid;                   // global row = b*S + s
        int s   = r & 2047;
        int hh  = t >> 4;                // head (0..15)
        int i8  = t & 15;                // 4-float group within head

        float4 r0 = rot4[s * 32 + 2 * i8];
        float4 r1 = rot4[s * 32 + 2 * i8 + 1];
        float2 g  = g2[hh * 2048 + s];

        long idx = (long)r * 1024 + t * 4;
        float4 xq = *(const float4*)(Q + idx);
        float4 xk = *(const float4*)(K + idx);

        float cq0 = r0.x * g.x, sq0 = r0.y * g.x;
        float ck0 = r0.z * g.y, sk0 = r0.w * g.y;
        float cq1 = r1.x * g.x, sq1 = r1.y * g.x;
        float ck1 = r1.z * g.y, sk1 = r1.w * g.y;

        float q0 = xq.x * cq0 - xq.y * sq0, q1 = xq.y * cq0 + xq.x * sq0;
        float q2 = xq.z * cq1 - xq.w * sq1, q3 = xq.w * cq1 + xq.z * sq1;
        float k0 = xk.x * ck0 - xk.y * sk0, k1 = xk.y * ck0 + xk.x * sk0;
        float k2 = xk.z * ck1 - xk.w * sk1, k3 = xk.w * ck1 + xk.z * sk1;

        *(uint2*)(qb + idx) = make_uint2((unsigned)f2bf(q0) | ((unsigned)f2bf(q1) << 16),
                                         (unsigned)f2bf(q2) | ((unsigned)f2bf(q3) << 16));
        *(uint2*)(kb + idx) = make_uint2((unsigned)f2bf(k0) | ((unsigned)f2bf(k1) << 16),
                                         (unsigned)f2bf(k2) | ((unsigned)f2bf(k3) << 16));
    } else {
        // ---- V transpose blocks (unchanged; vt layout [bh][d][s] kept for PV B-operand)
        int vb = bid - 4096;
        int bh = vb & 31;
        int b = bh >> 4, hh = bh & 15;
        int s0 = (vb >> 5) * 64;

#pragma unroll
        for (int it = 0; it < 4; ++it) {
            int f  = it * 256 + t;
            int sl = f >> 4;
            int d4 = f & 15;
            float4 v = *(const float4*)(V + ((long)(b * S_ + s0 + sl)) * 1024 + hh * 64 + d4 * 4);
            tile[sl * 65 + d4 * 4 + 0] = v.x;
            tile[sl * 65 + d4 * 4 + 1] = v.y;
            tile[sl * 65 + d4 * 4 + 2] = v.z;
            tile[sl * 65 + d4 * 4 + 3] = v.w;
        }
        __syncthreads();
        int d = t >> 2, c = t & 3;
        unsigned int pk[8];
#pragma unroll
        for (int jj = 0; jj < 8; ++jj) {
            float f0 = tile[(c * 16 + 2 * jj + 0) * 65 + d];
            float f1 = tile[(c * 16 + 2 * jj + 1) * 65 + d];
            pk[jj] = (unsigned int)f2bf(f0) | ((unsigned int)f2bf(f1) << 16);
        }
        unsigned short* outp = vt + ((long)(bh * 64 + d)) * S_ + s0 + c * 16;
        ((uint4*)outp)[0] = make_uint4(pk[0], pk[1], pk[2], pk[3]);
        ((uint4*)outp)[1] = make_uint4(pk[4], pk[5], pk[6], pk[7]);
    }
}

// ---------------- kernel 2: retention, kv-half wave-split (8 waves/block) ----------------
// ROUND-4 CHANGE: work-balanced (g,bh) <- blockIdx map. Block g walks 2g+2
// tiles (2..32, a 16x spread); with 512 blocks = exactly 2 resident/CU the
// critical path is the worst CU's tile sum. New map: flipping bit0 OR bit8 of
// blockIdx complements g (g -> 15-g), so under EITHER plausible co-residency
// (adjacent pair 2j/2j+1, or breadth-first pair i/i+256) every CU sums to 34
// tiles (old map: up to 64). Bijective over (g,bh); inner loop untouched.
__global__ __launch_bounds__(512, 4) void retention_kernel(const unsigned short* __restrict__ qb,
                                                           const unsigned short* __restrict__ kb,
                                                           const unsigned short* __restrict__ vt,
                                                           float* __restrict__ out) {
    __shared__ __align__(16) unsigned short KV[16384];        // [K0|V0|K1|V1], 4096 shorts each
    __shared__ __align__(16) unsigned short Ss[8][32 * SST];  // wave-private score strips
    unsigned short* K0 = KV;
    unsigned short* V0 = KV + 4096;
    unsigned short* K1 = KV + 8192;
    unsigned short* V1 = KV + 12288;

    int t = threadIdx.x;
    int w = t >> 6, lane = t & 63, quad = lane >> 4, l16 = lane & 15;
    int qw = w & 3;          // q-subtile (32 rows)
    int p  = w >> 2;         // kv-half (0: cols 0..31, 1: cols 32..63)

    // balanced dispatch map: i = [b8][c3][h4][b0]
    int i   = blockIdx.x;
    int bb0 = i & 1;
    int h4  = (i >> 1) & 15;
    int c3  = (i >> 5) & 7;
    int b8  = (i >> 8) & 1;
    int par = bb0 ^ b8;
    int g   = par ? (15 - h4) : h4;
    int bh  = c3 | (b8 << 3) | (bb0 << 4);
    int b = bh >> 4, hh = bh & 15;

    int q0w  = g * 128 + qw * 32;
    int dkt  = 2 * g + (qw >> 1);     // wave's diagonal KV tile
    int odd  = qw & 1;                // row offset within diagonal tile = odd*32
    int kvend = 2 * g + 2;            // tiles this block walks (even)

    const unsigned short* qB = qb + ((long)(b * S_ + q0w)) * 1024 + hh * 64;
    const unsigned short* kB = kb + ((long)(b * S_)) * 1024 + hh * 64;
    const unsigned short* vB = vt + (long)bh * 64 * S_;

    bf16x8_t aQ[2][2];
#pragma unroll
    for (int m = 0; m < 2; ++m)
#pragma unroll
        for (int kk = 0; kk < 2; ++kk)
            aQ[m][kk] = *(const bf16x8_t*)(qB + (long)(m * 16 + l16) * 1024 + kk * 32 + quad * 8);

    f32x4_t acc[2][4];   // partial O over this wave's kv-half
#pragma unroll
    for (int m = 0; m < 2; ++m)
#pragma unroll
        for (int nd = 0; nd < 4; ++nd) acc[m][nd] = (f32x4_t){0.f, 0.f, 0.f, 0.f};

    // stage one K+V tile: 8 waves x (1 K-instr + 1 V-instr), 1 KB each.
    // 16B block (row, c) stored at slot c ^ (row&7)  [bank swizzle]
    auto stage = [&](unsigned short* Kd, unsigned short* Vd, int kt) {
        const unsigned short* kSrc = kB + (long)kt * 64 * 1024;
        const unsigned short* vSrc = vB + kt * 64;
        int row = w * 8 + (lane >> 3);
        int c   = (lane & 7) ^ (row & 7);
        async16(kSrc + (long)row * 1024 + c * 8, Kd + w * 512);
        async16(vSrc + (long)row * S_ + c * 8, Vd + w * 512);
    };

    // one wave's slice of one tile: 32 q-rows x its 32 kv-cols
    auto computeHalf = [&](const unsigned short* Kt, const unsigned short* Vt, bool diag) {
        f32x4_t sc[2][2];
#pragma unroll
        for (int m = 0; m < 2; ++m)
#pragma unroll
            for (int ntl = 0; ntl < 2; ++ntl) sc[m][ntl] = (f32x4_t){0.f, 0.f, 0.f, 0.f};

#pragma unroll
        for (int kk = 0; kk < 2; ++kk)
#pragma unroll
            for (int ntl = 0; ntl < 2; ++ntl) {
                int krow = p * 32 + ntl * 16 + l16;
                bf16x8_t bk = *(const bf16x8_t*)&Kt[krow * 64 +
                                                   (((kk * 4 + quad) ^ (krow & 7)) * 8)];
                sc[0][ntl] = __builtin_amdgcn_mfma_f32_16x16x32_bf16(aQ[0][kk], bk, sc[0][ntl], 0, 0, 0);
                sc[1][ntl] = __builtin_amdgcn_mfma_f32_16x16x32_bf16(aQ[1][kk], bk, sc[1][ntl], 0, 0, 0);
            }

        unsigned short* ssw = Ss[w];
        if (!diag) {
#pragma unroll
            for (int m = 0; m < 2; ++m)
#pragma unroll
                for (int ntl = 0; ntl < 2; ++ntl)
#pragma unroll
                    for (int r = 0; r < 4; ++r)
                        ssw[(m * 16 + quad * 4 + r) * SST + ntl * 16 + l16] = f2bf(sc[m][ntl][r]);
        } else {   // p == odd triangular case: keep iff (quad*4+r) + (m-ntl)*16 >= l16
#pragma unroll
            for (int m = 0; m < 2; ++m)
#pragma unroll
                for (int ntl = 0; ntl < 2; ++ntl) {
                    int dlt = (m - ntl) * 16;
#pragma unroll
                    for (int r = 0; r < 4; ++r) {
                        int rr = quad * 4 + r;
                        float v = ((rr + dlt) >= l16) ? sc[m][ntl][r] : 0.0f;
                        ssw[(m * 16 + rr) * SST + ntl * 16 + l16] = f2bf(v);
                    }
                }
        }

        // PV: A = wave's 16x32 score strips, B = V^T chunks (kv-half p)
        bf16x8_t aS0 = *(const bf16x8_t*)&ssw[(0 * 16 + l16) * SST + quad * 8];
        bf16x8_t aS1 = *(const bf16x8_t*)&ssw[(1 * 16 + l16) * SST + quad * 8];
#pragma unroll
        for (int nd = 0; nd < 4; ++nd) {
            int vrow = nd * 16 + l16;
            bf16x8_t bv = *(const bf16x8_t*)&Vt[vrow * 64 +
                                               (((p * 4 + quad) ^ (vrow & 7)) * 8)];
            acc[0][nd] = __builtin_amdgcn_mfma_f32_16x16x32_bf16(aS0, bv, acc[0][nd], 0, 0, 0);
            acc[1][nd] = __builtin_amdgcn_mfma_f32_16x16x32_bf16(aS1, bv, acc[1][nd], 0, 0, 0);
        }
    };

    // wave computes tile kt iff kt < dkt, or kt == dkt and p <= odd
    // (p > odd: its kv-half is entirely above the diagonal -> all zero)
    stage(K0, V0, 0);
    for (int kt = 0; kt < kvend; kt += 2) {
        stage(K1, V1, kt + 1);
        WAITV2;                       // own tile-kt DMAs done; kt+1 stays in flight
        BAR;
        if (kt < dkt || (kt == dkt && p <= odd)) computeHalf(K0, V0, kt == dkt && p == odd);
        BAR;

        if (kt + 2 < kvend) { stage(K0, V0, kt + 2); WAITV2; }
        else                { WAITV0; }
        BAR;
        if (kt + 1 < dkt || (kt + 1 == dkt && p <= odd))
            computeHalf(K1, V1, kt + 1 == dkt && p == odd);
        BAR;
    }

    // ---- reduce the two kv-half partials (overlay scratch on dead K/V buffers) ----
    float* red = (float*)KV;          // 8192 floats; 2048 per qw
    if (p == 1) {
#pragma unroll
        for (int m = 0; m < 2; ++m)
#pragma unroll
            for (int nd = 0; nd < 4; ++nd)
#pragma unroll
                for (int r = 0; r < 4; ++r)
                    red[qw * 2048 + (m * 16 + quad * 4 + r) * 64 + nd * 16 + l16] = acc[m][nd][r];
    }
    BAR;
    if (p == 0) {
#pragma unroll
        for (int m = 0; m < 2; ++m)
#pragma unroll
            for (int nd = 0; nd < 4; ++nd)
#pragma unroll
                for (int r = 0; r < 4; ++r) {
                    int row = q0w + m * 16 + quad * 4 + r;
                    float v = acc[m][nd][r] +
                              red[qw * 2048 + (m * 16 + quad * 4 + r) * 64 + nd * 16 + l16];
                    out[((long)(b * S_ + row)) * 1024 + hh * 64 + nd * 16 + l16] = v;
                }
    }
}

extern "C" void kernel_launch(void* const* d_in, const int* in_sizes, int n_in,
                              void* d_out, int out_size, void* d_ws, size_t ws_size,
                              hipStream_t stream) {
    const float* Q = (const float*)d_in[0];
    const float* K = (const float*)d_in[1];
    const float* V = (const float*)d_in[2];
    float* out = (float*)d_out;

    const size_t perBuf = (size_t)B_ * H_ * S_ * D_;
    unsigned short* qb = (unsigned short*)d_ws;
    unsigned short* kb = qb + perBuf;
    unsigned short* vt = kb + perBuf;

    // tables: 1 MB rot4 + 256 KB g2. Prefer workspace tail; fall back to d_out
    // (legal scratch: retention_kernel fully overwrites out afterward, stream-ordered).
    const size_t bufBytes = 3 * perBuf * sizeof(unsigned short);
    const size_t tblBytes = (size_t)S_ * 32 * sizeof(float4) + (size_t)H_ * S_ * sizeof(float2);
    char* tbl;
    if (ws_size >= bufBytes + tblBytes) tbl = (char*)d_ws + bufBytes;
    else                                tbl = (char*)d_out;
    float4* rot4 = (float4*)tbl;
    float2* g2   = (float2*)(rot4 + (size_t)S_ * 32);

    hipLaunchKernelGGL(table_kernel, dim3(256), dim3(256), 0, stream, rot4, g2);
    hipLaunchKernelGGL(prep_kernel, dim3(5120), dim3(256), 0, stream, Q, K, V, rot4, g2, qb, kb, vt);
    hipLaunchKernelGGL(retention_kernel, dim3(512), dim3(512), 0, stream, qb, kb, vt, out);
}

// Round 6
// 125.405 us; speedup vs baseline: 1.0194x; 1.0194x over previous
//
#include <hip/hip_runtime.h>
#include <hip/hip_bf16.h>
#include <math.h>

#define B_  2
#define S_  2048
#define H_  16
#define D_  64
#define SST 40   // score-strip stride (shorts): 80 B rows, 16B-aligned

typedef __attribute__((ext_vector_type(8))) short bf16x8_t;
typedef __attribute__((ext_vector_type(4))) float f32x4_t;

__device__ __forceinline__ unsigned short f2bf(float f) {
    __hip_bfloat16 h = __float2bfloat16(f);
    return __builtin_bit_cast(unsigned short, h);
}

// async global->LDS, 16B per lane; LDS dest = wave-uniform base + lane*16
__device__ __forceinline__ void async16(const unsigned short* g, unsigned short* l) {
    __builtin_amdgcn_global_load_lds(
        (const __attribute__((address_space(1))) unsigned int*)g,
        (__attribute__((address_space(3))) unsigned int*)l, 16, 0, 0);
}

#define WAITV2 asm volatile("s_waitcnt vmcnt(2)" ::: "memory")
#define WAITV0 asm volatile("s_waitcnt vmcnt(0)" ::: "memory")
#define BAR    asm volatile("s_barrier" ::: "memory")

// ---------------- kernel 1: fused prep (tables-in-LDS + QK ILP + V transpose) ----
// 1024 blocks x 256 threads; LDS 19.2 KB -> 8 blocks/CU (32 waves).
// NO cooperative launch (round-5 lesson: coop launch breaks harness graph capture).
// P1: per-block rot/decay factors in LDS for the block's 4 rows (replaces the
//     separate table kernel + its global round-trip).
// P2: QK rotate+decay, 4 rows: thread t handles chunk t of each row, unrolled
//     -> 8 independent float4 loads in flight (round-3 prep had 2: MLP-starved,
//     which is the revised theory of why "streaming" prep stayed ~45 us).
// P3: V transpose, 1 tile/block (proven code).
__global__ __launch_bounds__(256) void prep_kernel(const float* __restrict__ Q,
                                                   const float* __restrict__ K,
                                                   const float* __restrict__ V,
                                                   unsigned short* __restrict__ qb,
                                                   unsigned short* __restrict__ kb,
                                                   unsigned short* __restrict__ vt) {
    __shared__ float  tile[64 * 65];     // 16640 B (P3)
    __shared__ float4 rotq[4 * 32];      //  2048 B (P1/P2)
    __shared__ float  gl[4 * 16 * 2];    //   512 B (P1/P2)
    int t   = threadIdx.x;
    int bid = blockIdx.x;

    // ---- P1: factor tables for rows bid*4 .. bid*4+3
    if (t < 128) {
        int sl = t >> 5, i = t & 31;
        int s  = (bid * 4 + sl) & 2047;
        float pos = (float)s;
        float bsc  = (2.0f * (float)i + 25.6f) / 89.6f;
        float xsc  = exp2f(log2f(bsc) * pos * (1.0f / 512.0f));
        float invf = exp2f(-(float)i * (13.287712379549449f / 32.0f));
        float ang  = pos * invf;
        float kq = rintf(ang * 0.15915494309189535f);
        float rr = fmaf(kq, -6.2831853071795865f, ang);
        float sn = sinf(rr), cs = cosf(rr);
        float rxs = 1.0f / xsc;
        rotq[sl * 32 + i] = make_float4(cs * xsc, sn * xsc, cs * rxs, sn * rxs);
    } else {
        int u  = t - 128;
        int sl = u >> 5, hh = (u >> 1) & 15, pm = u & 1;
        int s  = (bid * 4 + sl) & 2047;
        float lnv = -3.4657359027997265f + (float)hh * (-0.18483924814931874f);
        float l2g = log2f(1.0f - expf(lnv));
        gl[(sl * 16 + hh) * 2 + pm] = exp2f((pm ? -(float)s : (float)s) * l2g);
    }
    __syncthreads();

    // ---- P2: QK rotate+decay, 4 rows; 8 independent loads in flight
    {
        int hh = t >> 4, i8 = t & 15;
#pragma unroll
        for (int j = 0; j < 4; ++j) {
            int r = bid * 4 + j;             // global row = b*S + s
            float4 r0 = rotq[j * 32 + 2 * i8];
            float4 r1 = rotq[j * 32 + 2 * i8 + 1];
            float gx = gl[(j * 16 + hh) * 2 + 0];
            float gy = gl[(j * 16 + hh) * 2 + 1];

            long idx = (long)r * 1024 + t * 4;
            float4 xq = *(const float4*)(Q + idx);
            float4 xk = *(const float4*)(K + idx);

            float cq0 = r0.x * gx, sq0 = r0.y * gx;
            float ck0 = r0.z * gy, sk0 = r0.w * gy;
            float cq1 = r1.x * gx, sq1 = r1.y * gx;
            float ck1 = r1.z * gy, sk1 = r1.w * gy;

            float q0 = xq.x * cq0 - xq.y * sq0, q1 = xq.y * cq0 + xq.x * sq0;
            float q2 = xq.z * cq1 - xq.w * sq1, q3 = xq.w * cq1 + xq.z * sq1;
            float k0 = xk.x * ck0 - xk.y * sk0, k1 = xk.y * ck0 + xk.x * sk0;
            float k2 = xk.z * ck1 - xk.w * sk1, k3 = xk.w * ck1 + xk.z * sk1;

            *(uint2*)(qb + idx) = make_uint2((unsigned)f2bf(q0) | ((unsigned)f2bf(q1) << 16),
                                             (unsigned)f2bf(q2) | ((unsigned)f2bf(q3) << 16));
            *(uint2*)(kb + idx) = make_uint2((unsigned)f2bf(k0) | ((unsigned)f2bf(k1) << 16),
                                             (unsigned)f2bf(k2) | ((unsigned)f2bf(k3) << 16));
        }
    }
    __syncthreads();

    // ---- P3: V transpose, tile bid (proven code; vt layout [bh][d][s])
    {
        int bh = bid & 31;
        int b = bh >> 4, hh = bh & 15;
        int s0 = (bid >> 5) * 64;

#pragma unroll
        for (int it = 0; it < 4; ++it) {
            int f  = it * 256 + t;
            int sl = f >> 4;
            int d4 = f & 15;
            float4 v = *(const float4*)(V + ((long)(b * S_ + s0 + sl)) * 1024 + hh * 64 + d4 * 4);
            tile[sl * 65 + d4 * 4 + 0] = v.x;
            tile[sl * 65 + d4 * 4 + 1] = v.y;
            tile[sl * 65 + d4 * 4 + 2] = v.z;
            tile[sl * 65 + d4 * 4 + 3] = v.w;
        }
        __syncthreads();
        int d = t >> 2, c = t & 3;
        unsigned int pk[8];
#pragma unroll
        for (int jj = 0; jj < 8; ++jj) {
            float f0 = tile[(c * 16 + 2 * jj + 0) * 65 + d];
            float f1 = tile[(c * 16 + 2 * jj + 1) * 65 + d];
            pk[jj] = (unsigned int)f2bf(f0) | ((unsigned int)f2bf(f1) << 16);
        }
        unsigned short* outp = vt + ((long)(bh * 64 + d)) * S_ + s0 + c * 16;
        ((uint4*)outp)[0] = make_uint4(pk[0], pk[1], pk[2], pk[3]);
        ((uint4*)outp)[1] = make_uint4(pk[4], pk[5], pk[6], pk[7]);
    }
}

// ---------------- kernel 2: retention, kv-half wave-split (8 waves/block) ----------------
// Verbatim round 4 (last passing version; balanced dispatch map kept).
__global__ __launch_bounds__(512, 4) void retention_kernel(const unsigned short* __restrict__ qb,
                                                           const unsigned short* __restrict__ kb,
                                                           const unsigned short* __restrict__ vt,
                                                           float* __restrict__ out) {
    __shared__ __align__(16) unsigned short KV[16384];        // [K0|V0|K1|V1], 4096 shorts each
    __shared__ __align__(16) unsigned short Ss[8][32 * SST];  // wave-private score strips
    unsigned short* K0 = KV;
    unsigned short* V0 = KV + 4096;
    unsigned short* K1 = KV + 8192;
    unsigned short* V1 = KV + 12288;

    int t = threadIdx.x;
    int w = t >> 6, lane = t & 63, quad = lane >> 4, l16 = lane & 15;
    int qw = w & 3;          // q-subtile (32 rows)
    int p  = w >> 2;         // kv-half (0: cols 0..31, 1: cols 32..63)

    // balanced dispatch map: i = [b8][c3][h4][b0]
    int i   = blockIdx.x;
    int bb0 = i & 1;
    int h4  = (i >> 1) & 15;
    int c3  = (i >> 5) & 7;
    int b8  = (i >> 8) & 1;
    int par = bb0 ^ b8;
    int g   = par ? (15 - h4) : h4;
    int bh  = c3 | (b8 << 3) | (bb0 << 4);
    int b = bh >> 4, hh = bh & 15;

    int q0w  = g * 128 + qw * 32;
    int dkt  = 2 * g + (qw >> 1);     // wave's diagonal KV tile
    int odd  = qw & 1;                // row offset within diagonal tile = odd*32
    int kvend = 2 * g + 2;            // tiles this block walks (even)

    const unsigned short* qB = qb + ((long)(b * S_ + q0w)) * 1024 + hh * 64;
    const unsigned short* kB = kb + ((long)(b * S_)) * 1024 + hh * 64;
    const unsigned short* vB = vt + (long)bh * 64 * S_;

    bf16x8_t aQ[2][2];
#pragma unroll
    for (int m = 0; m < 2; ++m)
#pragma unroll
        for (int kk = 0; kk < 2; ++kk)
            aQ[m][kk] = *(const bf16x8_t*)(qB + (long)(m * 16 + l16) * 1024 + kk * 32 + quad * 8);

    f32x4_t acc[2][4];   // partial O over this wave's kv-half
#pragma unroll
    for (int m = 0; m < 2; ++m)
#pragma unroll
        for (int nd = 0; nd < 4; ++nd) acc[m][nd] = (f32x4_t){0.f, 0.f, 0.f, 0.f};

    // stage one K+V tile: 8 waves x (1 K-instr + 1 V-instr), 1 KB each.
    // 16B block (row, c) stored at slot c ^ (row&7)  [bank swizzle]
    auto stage = [&](unsigned short* Kd, unsigned short* Vd, int kt) {
        const unsigned short* kSrc = kB + (long)kt * 64 * 1024;
        const unsigned short* vSrc = vB + kt * 64;
        int row = w * 8 + (lane >> 3);
        int c   = (lane & 7) ^ (row & 7);
        async16(kSrc + (long)row * 1024 + c * 8, Kd + w * 512);
        async16(vSrc + (long)row * S_ + c * 8, Vd + w * 512);
    };

    // one wave's slice of one tile: 32 q-rows x its 32 kv-cols
    auto computeHalf = [&](const unsigned short* Kt, const unsigned short* Vt, bool diag) {
        f32x4_t sc[2][2];
#pragma unroll
        for (int m = 0; m < 2; ++m)
#pragma unroll
            for (int ntl = 0; ntl < 2; ++ntl) sc[m][ntl] = (f32x4_t){0.f, 0.f, 0.f, 0.f};

#pragma unroll
        for (int kk = 0; kk < 2; ++kk)
#pragma unroll
            for (int ntl = 0; ntl < 2; ++ntl) {
                int krow = p * 32 + ntl * 16 + l16;
                bf16x8_t bk = *(const bf16x8_t*)&Kt[krow * 64 +
                                                   (((kk * 4 + quad) ^ (krow & 7)) * 8)];
                sc[0][ntl] = __builtin_amdgcn_mfma_f32_16x16x32_bf16(aQ[0][kk], bk, sc[0][ntl], 0, 0, 0);
                sc[1][ntl] = __builtin_amdgcn_mfma_f32_16x16x32_bf16(aQ[1][kk], bk, sc[1][ntl], 0, 0, 0);
            }

        unsigned short* ssw = Ss[w];
        if (!diag) {
#pragma unroll
            for (int m = 0; m < 2; ++m)
#pragma unroll
                for (int ntl = 0; ntl < 2; ++ntl)
#pragma unroll
                    for (int r = 0; r < 4; ++r)
                        ssw[(m * 16 + quad * 4 + r) * SST + ntl * 16 + l16] = f2bf(sc[m][ntl][r]);
        } else {   // p == odd triangular case: keep iff (quad*4+r) + (m-ntl)*16 >= l16
#pragma unroll
            for (int m = 0; m < 2; ++m)
#pragma unroll
                for (int ntl = 0; ntl < 2; ++ntl) {
                    int dlt = (m - ntl) * 16;
#pragma unroll
                    for (int r = 0; r < 4; ++r) {
                        int rr = quad * 4 + r;
                        float v = ((rr + dlt) >= l16) ? sc[m][ntl][r] : 0.0f;
                        ssw[(m * 16 + rr) * SST + ntl * 16 + l16] = f2bf(v);
                    }
                }
        }

        // PV: A = wave's 16x32 score strips, B = V^T chunks (kv-half p)
        bf16x8_t aS0 = *(const bf16x8_t*)&ssw[(0 * 16 + l16) * SST + quad * 8];
        bf16x8_t aS1 = *(const bf16x8_t*)&ssw[(1 * 16 + l16) * SST + quad * 8];
#pragma unroll
        for (int nd = 0; nd < 4; ++nd) {
            int vrow = nd * 16 + l16;
            bf16x8_t bv = *(const bf16x8_t*)&Vt[vrow * 64 +
                                               (((p * 4 + quad) ^ (vrow & 7)) * 8)];
            acc[0][nd] = __builtin_amdgcn_mfma_f32_16x16x32_bf16(aS0, bv, acc[0][nd], 0, 0, 0);
            acc[1][nd] = __builtin_amdgcn_mfma_f32_16x16x32_bf16(aS1, bv, acc[1][nd], 0, 0, 0);
        }
    };

    // wave computes tile kt iff kt < dkt, or kt == dkt and p <= odd
    // (p > odd: its kv-half is entirely above the diagonal -> all zero)
    stage(K0, V0, 0);
    for (int kt = 0; kt < kvend; kt += 2) {
        stage(K1, V1, kt + 1);
        WAITV2;                       // own tile-kt DMAs done; kt+1 stays in flight
        BAR;
        if (kt < dkt || (kt == dkt && p <= odd)) computeHalf(K0, V0, kt == dkt && p == odd);
        BAR;

        if (kt + 2 < kvend) { stage(K0, V0, kt + 2); WAITV2; }
        else                { WAITV0; }
        BAR;
        if (kt + 1 < dkt || (kt + 1 == dkt && p <= odd))
            computeHalf(K1, V1, kt + 1 == dkt && p == odd);
        BAR;
    }

    // ---- reduce the two kv-half partials (overlay scratch on dead K/V buffers) ----
    float* red = (float*)KV;          // 8192 floats; 2048 per qw
    if (p == 1) {
#pragma unroll
        for (int m = 0; m < 2; ++m)
#pragma unroll
            for (int nd = 0; nd < 4; ++nd)
#pragma unroll
                for (int r = 0; r < 4; ++r)
                    red[qw * 2048 + (m * 16 + quad * 4 + r) * 64 + nd * 16 + l16] = acc[m][nd][r];
    }
    BAR;
    if (p == 0) {
#pragma unroll
        for (int m = 0; m < 2; ++m)
#pragma unroll
            for (int nd = 0; nd < 4; ++nd)
#pragma unroll
                for (int r = 0; r < 4; ++r) {
                    int row = q0w + m * 16 + quad * 4 + r;
                    float v = acc[m][nd][r] +
                              red[qw * 2048 + (m * 16 + quad * 4 + r) * 64 + nd * 16 + l16];
                    out[((long)(b * S_ + row)) * 1024 + hh * 64 + nd * 16 + l16] = v;
                }
    }
}

extern "C" void kernel_launch(void* const* d_in, const int* in_sizes, int n_in,
                              void* d_out, int out_size, void* d_ws, size_t ws_size,
                              hipStream_t stream) {
    const float* Q = (const float*)d_in[0];
    const float* K = (const float*)d_in[1];
    const float* V = (const float*)d_in[2];
    float* out = (float*)d_out;

    const size_t perBuf = (size_t)B_ * H_ * S_ * D_;
    unsigned short* qb = (unsigned short*)d_ws;
    unsigned short* kb = qb + perBuf;
    unsigned short* vt = kb + perBuf;

    hipLaunchKernelGGL(prep_kernel, dim3(1024), dim3(256), 0, stream, Q, K, V, qb, kb, vt);
    hipLaunchKernelGGL(retention_kernel, dim3(512), dim3(512), 0, stream, qb, kb, vt, out);
}